// Round 1
// baseline (405.425 us; speedup 1.0000x reference)
//
#include <hip/hip_runtime.h>

// Conv2d VALID 3x3: x[32][64][112][112] f32, w[128][64][3][3] f32 -> out[32][128][110][110] f32
// Implicit GEMM on bf16 MFMA 16x16x32. K-order = (kh,kw,ci) so k-runs of 8 are contiguous ci.
// Block: 128 co x 256 p (16oh x 16ow). 4 waves, each 128co x 64p = 8x4 MFMA tiles.
// LDS: x-window [18][18] px channels-last (64ci bf16, padded to 72 shorts = 144B) staged ONCE,
//      W plane [128co][64ci] (padded 72) staged per (kh,kw) from pre-permuted ws copy.

typedef short bf16x8 __attribute__((ext_vector_type(8)));
typedef float f32x4 __attribute__((ext_vector_type(4)));

__device__ __forceinline__ unsigned short f2bf(float f) {
    unsigned int u = __builtin_bit_cast(unsigned int, f);
    unsigned int r = u + 0x7fffu + ((u >> 16) & 1u);   // RNE
    return (unsigned short)(r >> 16);
}

// ws layout: wp[kh*3+kw][co][ci] bf16, 9*128*64 = 73728 elems = 147456 B
__global__ void wperm_kernel(const float* __restrict__ W, unsigned short* __restrict__ wp) {
    int t = blockIdx.x * 256 + threadIdx.x;
    if (t < 73728) {
        int r  = t >> 13;          // (kh*3+kw)
        int co = (t >> 6) & 127;
        int ci = t & 63;
        wp[t] = f2bf(W[(co * 64 + ci) * 9 + r]);
    }
}

__global__ __launch_bounds__(256, 2) void conv_mfma(const float* __restrict__ x,
                                                    const unsigned short* __restrict__ wp,
                                                    float* __restrict__ out) {
    // pixel stride 72 shorts = 144 B  -> 36 dwords = 4 mod 32 banks: conflict-free b128 reads
    __shared__ alignas(16) unsigned short xwin[324 * 72];   // 18*18 px * (64ci + 8 pad) = 46656 B
    __shared__ alignas(16) unsigned short wpl[128 * 72];    // 128co * (64ci + 8 pad)   = 18432 B

    const int tid  = threadIdx.x;
    const int lane = tid & 63;
    const int wv   = tid >> 6;        // wave 0..3 -> oh rows wv*4..wv*4+3
    const int quad = lane >> 4;
    const int l15  = lane & 15;

    const int b    = blockIdx.x / 49;
    const int tile = blockIdx.x % 49;
    const int oh0  = (tile / 7) * 16;
    const int ow0  = (tile % 7) * 16;

    // ---- stage x window (once): channels-last bf16 ----
    const float* xb = x + b * 64 * 12544;                   // 112*112 = 12544
    for (int task = tid; task < 288; task += 256) {         // 16 ci-groups x 18 h-rows
        const int cg = task / 18;                           // ci = cg*4 .. +3
        const int hh = task % 18;
        const int h  = min(oh0 + hh, 111);
        const float* xr = xb + (cg * 4) * 12544 + h * 112;
        unsigned short* dst = &xwin[(hh * 18) * 72 + cg * 4];
        #pragma unroll
        for (int ww = 0; ww < 18; ww++) {
            const int w = min(ow0 + ww, 111);               // clamped reads feed only discarded outputs
            uint2 v;
            v.x = (unsigned)f2bf(xr[w])         | ((unsigned)f2bf(xr[12544 + w]) << 16);
            v.y = (unsigned)f2bf(xr[25088 + w]) | ((unsigned)f2bf(xr[37632 + w]) << 16);
            *reinterpret_cast<uint2*>(dst + ww * 72) = v;   // pix*144 + cg*8 bytes, 8-aligned
        }
    }

    f32x4 acc[8][4];
    const f32x4 zero = {0.0f, 0.0f, 0.0f, 0.0f};
    #pragma unroll
    for (int mt = 0; mt < 8; mt++)
        #pragma unroll
        for (int nt = 0; nt < 4; nt++) acc[mt][nt] = zero;

    for (int r = 0; r < 9; r++) {
        const int kh = r / 3;
        const int kw = r % 3;

        __syncthreads();                                    // protect previous plane's reads
        {   // stage W plane r: coalesced 16B copies from ws
            const unsigned short* src = wp + r * 8192;
            #pragma unroll
            for (int j = 0; j < 4; j++) {
                const int k   = tid + 256 * j;              // 16B chunk id, 0..1023
                const int co  = k >> 3;
                const int ci0 = (k & 7) * 8;
                uint4 v = *reinterpret_cast<const uint4*>(src + k * 8);
                *reinterpret_cast<uint4*>(&wpl[co * 72 + ci0]) = v;
            }
        }
        __syncthreads();

        #pragma unroll
        for (int cs = 0; cs < 2; cs++) {
            const int ko = cs * 32 + quad * 8;              // lane's ci start
            bf16x8 bfrag[4];
            #pragma unroll
            for (int nt = 0; nt < 4; nt++) {
                const int t = wv * 4 + nt;                  // local oh row
                bfrag[nt] = *reinterpret_cast<const bf16x8*>(
                    &xwin[((t + kh) * 18 + (l15 + kw)) * 72 + ko]);
            }
            #pragma unroll
            for (int mt = 0; mt < 8; mt++) {
                bf16x8 afrag = *reinterpret_cast<const bf16x8*>(
                    &wpl[(mt * 16 + l15) * 72 + ko]);
                #pragma unroll
                for (int nt = 0; nt < 4; nt++)
                    acc[mt][nt] = __builtin_amdgcn_mfma_f32_16x16x32_bf16(
                        afrag, bfrag[nt], acc[mt][nt], 0, 0, 0);
            }
        }
    }

    // ---- epilogue: D layout col(n=ow)=lane&15, row(m-part)=quad*4+reg ----
    const int owc = ow0 + l15;
    if (owc < 110) {
        float* ob = out + b * 128 * 12100;                  // 110*110 = 12100
        #pragma unroll
        for (int mt = 0; mt < 8; mt++) {
            #pragma unroll
            for (int nt = 0; nt < 4; nt++) {
                const int oh = oh0 + wv * 4 + nt;
                if (oh < 110) {
                    #pragma unroll
                    for (int reg = 0; reg < 4; reg++) {
                        const int co = mt * 16 + quad * 4 + reg;
                        ob[(co * 110 + oh) * 110 + owc] = acc[mt][nt][reg];
                    }
                }
            }
        }
    }
}

extern "C" void kernel_launch(void* const* d_in, const int* in_sizes, int n_in,
                              void* d_out, int out_size, void* d_ws, size_t ws_size,
                              hipStream_t stream) {
    const float* x = (const float*)d_in[0];      // 32*64*112*112
    const float* W = (const float*)d_in[1];      // 128*64*3*3
    float* out = (float*)d_out;                  // 32*128*110*110
    unsigned short* wp = (unsigned short*)d_ws;  // needs 147456 B

    wperm_kernel<<<288, 256, 0, stream>>>(W, wp);
    conv_mfma<<<32 * 49, 256, 0, stream>>>(x, wp, out);
}